// Round 1
// baseline (627.117 us; speedup 1.0000x reference)
//
#include <hip/hip_runtime.h>

#define NA   312      // attributes
#define LAT  64       // latent per attribute
#define HID  128      // hidden per attribute
#define NB   8192     // batch
#define RPB  256      // rows per block
#define NBT  (NB / RPB)   // 32 batch tiles

// One block: attribute a, 256 batch rows. W1[a] staged in LDS (32 KB),
// per-thread x row slice in 64 VGPRs, 8 hidden-column accumulators.
// All LDS reads in the hot loop are wave-uniform -> broadcast, no conflicts.
__global__ __launch_bounds__(256, 4) void attr_decoder_f32(
    const float* __restrict__ x,
    const float* __restrict__ W1,
    const float* __restrict__ b1,
    const float* __restrict__ W2,
    const float* __restrict__ b2,
    float* __restrict__ out)
{
    __shared__ float4 w1s[LAT * HID / 4];   // 32 KB, [k][j/4] layout
    __shared__ float  b1s[HID];
    __shared__ float  w2s[HID];
    __shared__ float  b2s;

    const int tid = threadIdx.x;
    const int a   = blockIdx.x / NBT;   // 32 consecutive blocks share W1[a] (L2 reuse)
    const int bt  = blockIdx.x % NBT;

    // ---- stage W1[a], b1[a], W2[a], b2[a] into LDS (coalesced float4) ----
    const float4* w1g = reinterpret_cast<const float4*>(W1) + (size_t)a * (LAT * HID / 4);
    #pragma unroll
    for (int i = 0; i < (LAT * HID / 4) / RPB; ++i)   // 8 iters
        w1s[i * RPB + tid] = w1g[i * RPB + tid];
    if (tid < HID) {
        b1s[tid] = b1[a * HID + tid];
        w2s[tid] = W2[a * HID + tid];   // W2 is [A, HID, 1] -> flat [A*HID]
    }
    if (tid == 0) b2s = b2[a];
    __syncthreads();

    // ---- per-thread row: load x[r, a*64 .. a*64+64) into registers ----
    const int r = bt * RPB + tid;
    const float4* xg = reinterpret_cast<const float4*>(
        x + (size_t)r * (NA * LAT) + (size_t)a * LAT);
    float xr[LAT];
    #pragma unroll
    for (int i = 0; i < LAT / 4; ++i) {
        float4 v = xg[i];
        xr[4*i+0] = v.x; xr[4*i+1] = v.y;
        xr[4*i+2] = v.z; xr[4*i+3] = v.w;
    }

    // ---- h = relu(x*W1 + b1); o = sigmoid(h*W2 + b2), 8 cols at a time ----
    float oacc = b2s;
    #pragma unroll 1
    for (int j = 0; j < HID; j += 8) {
        float acc[8];
        #pragma unroll
        for (int u = 0; u < 8; ++u) acc[u] = b1s[j + u];
        #pragma unroll
        for (int k = 0; k < LAT; ++k) {        // fully unrolled: static xr index
            const float4 wa = w1s[k * (HID/4) + (j >> 2)];
            const float4 wb = w1s[k * (HID/4) + (j >> 2) + 1];
            const float xk = xr[k];
            acc[0] = fmaf(xk, wa.x, acc[0]);
            acc[1] = fmaf(xk, wa.y, acc[1]);
            acc[2] = fmaf(xk, wa.z, acc[2]);
            acc[3] = fmaf(xk, wa.w, acc[3]);
            acc[4] = fmaf(xk, wb.x, acc[4]);
            acc[5] = fmaf(xk, wb.y, acc[5]);
            acc[6] = fmaf(xk, wb.z, acc[6]);
            acc[7] = fmaf(xk, wb.w, acc[7]);
        }
        #pragma unroll
        for (int u = 0; u < 8; ++u)
            oacc = fmaf(fmaxf(acc[u], 0.0f), w2s[j + u], oacc);
    }

    out[(size_t)r * NA + a] = 1.0f / (1.0f + __expf(-oacc));
}

extern "C" void kernel_launch(void* const* d_in, const int* in_sizes, int n_in,
                              void* d_out, int out_size, void* d_ws, size_t ws_size,
                              hipStream_t stream) {
    const float* x  = (const float*)d_in[0];
    const float* W1 = (const float*)d_in[1];
    const float* b1 = (const float*)d_in[2];
    const float* W2 = (const float*)d_in[3];
    const float* b2 = (const float*)d_in[4];
    float* out = (float*)d_out;

    dim3 grid(NA * NBT);   // 312 * 32 = 9984 blocks
    dim3 block(RPB);
    hipLaunchKernelGGL(attr_decoder_f32, grid, block, 0, stream,
                       x, W1, b1, W2, b2, out);
}

// Round 2
// 209.863 us; speedup vs baseline: 2.9882x; 2.9882x over previous
//
#include <hip/hip_runtime.h>

#define NA   312      // attributes
#define LAT  64       // latent per attribute (K)
#define HID  128      // hidden per attribute (N)
#define NB   8192     // batch
#define MB   128      // rows per block
#define NBT  (NB / MB)   // 64 batch tiles

typedef __attribute__((ext_vector_type(8))) short bf16x8;
typedef __attribute__((ext_vector_type(4))) float f32x4;

// fp32 -> bf16, round-to-nearest-even (branch-free; inputs are finite)
__device__ inline short f2bf(float f) {
    unsigned u = __builtin_bit_cast(unsigned, f);
    u += 0x7FFFu + ((u >> 16) & 1u);
    return (short)(u >> 16);
}

// One block: attribute a, 128 batch rows, 4 waves x 32 rows.
// Layer 1: bf16 MFMA 16x16x32 (A = x rows direct from global, B = W1 from
// swizzled LDS). Layer 2 + bias + sigmoid in fp32, in-wave reduction.
__global__ __launch_bounds__(256, 4) void attr_decoder_mfma(
    const float* __restrict__ x,
    const float* __restrict__ W1,
    const float* __restrict__ b1,
    const float* __restrict__ W2,
    const float* __restrict__ b2,
    float* __restrict__ out)
{
    __shared__ short w1T[HID * LAT];   // 16 KB bf16, [n][k], XOR-swizzled
    __shared__ float b1s[HID];
    __shared__ float w2s[HID];
    __shared__ float b2s_;

    const int tid = threadIdx.x;
    const int a   = blockIdx.x >> 6;   // 64 consecutive blocks share W1[a]
    const int bt  = blockIdx.x & (NBT - 1);

    // ---- stage W1[a] -> bf16, transposed to [n][k], swizzle byte^=(n&7)<<4 ----
    {
        const float4* wg = reinterpret_cast<const float4*>(W1 + (size_t)a * (LAT * HID));
        char* w1b = reinterpret_cast<char*>(w1T);
        #pragma unroll
        for (int i = 0; i < (LAT * HID / 4) / 256; ++i) {   // 8 iters
            const int flat4 = i * 256 + tid;
            float4 v = wg[flat4];
            const int flat = flat4 * 4;        // = k*128 + n0, n fast
            const int k  = flat >> 7;
            const int n0 = flat & 127;
            float vv[4] = {v.x, v.y, v.z, v.w};
            #pragma unroll
            for (int j = 0; j < 4; ++j) {
                const int n = n0 + j;
                const int byteaddr = (n * 128 + k * 2) ^ ((n & 7) << 4);
                *reinterpret_cast<short*>(w1b + byteaddr) = f2bf(vv[j]);
            }
        }
        if (tid < HID) {
            b1s[tid] = b1[a * HID + tid];
            w2s[tid] = W2[a * HID + tid];   // W2 flat [A*HID]
        }
        if (tid == 0) b2s_ = b2[a];
    }
    __syncthreads();

    const int w    = tid >> 6;        // wave id 0..3
    const int lane = tid & 63;
    const int llo  = lane & 15;
    const int lhi  = lane >> 4;
    const int rowbase = bt * MB + w * 32;

    // ---- A fragments: x rows straight from global, fp32 -> bf16 ----
    // A[m][k]: m = lane&15, k = (lane>>4)*8 + j  (per 16x16x32 layout)
    bf16x8 afrag[2][2];   // [mt][kk]
    #pragma unroll
    for (int mt = 0; mt < 2; ++mt) {
        const float* xrow = x + (size_t)(rowbase + mt * 16 + llo) * (NA * LAT)
                              + (size_t)a * LAT;
        #pragma unroll
        for (int kk = 0; kk < 2; ++kk) {
            const float4* p = reinterpret_cast<const float4*>(xrow + kk * 32 + lhi * 8);
            float4 v0 = p[0];
            float4 v1 = p[1];
            bf16x8 f;
            f[0] = f2bf(v0.x); f[1] = f2bf(v0.y); f[2] = f2bf(v0.z); f[3] = f2bf(v0.w);
            f[4] = f2bf(v1.x); f[5] = f2bf(v1.y); f[6] = f2bf(v1.z); f[7] = f2bf(v1.w);
            afrag[mt][kk] = f;
        }
    }

    // ---- layer 1 MFMA + fused layer-2 partials ----
    const char* w1b = reinterpret_cast<const char*>(w1T);
    float p2[2][4] = {};   // [mt][reg] partial sums of relu(h)*w2
    #pragma unroll
    for (int nt = 0; nt < 8; ++nt) {
        const int n = nt * 16 + llo;
        bf16x8 bfrag[2];
        #pragma unroll
        for (int kk = 0; kk < 2; ++kk) {
            const int byteaddr = (n * 128 + (kk * 32 + lhi * 8) * 2) ^ ((n & 7) << 4);
            bfrag[kk] = *reinterpret_cast<const bf16x8*>(w1b + byteaddr);
        }
        const float w2v = w2s[n];
        const float b1v = b1s[n];
        #pragma unroll
        for (int mt = 0; mt < 2; ++mt) {
            f32x4 acc = {0.f, 0.f, 0.f, 0.f};
            acc = __builtin_amdgcn_mfma_f32_16x16x32_bf16(afrag[mt][0], bfrag[0], acc, 0, 0, 0);
            acc = __builtin_amdgcn_mfma_f32_16x16x32_bf16(afrag[mt][1], bfrag[1], acc, 0, 0, 0);
            #pragma unroll
            for (int r = 0; r < 4; ++r) {
                const float h = fmaxf(acc[r] + b1v, 0.f);
                p2[mt][r] = fmaf(h, w2v, p2[mt][r]);
            }
        }
    }

    // ---- in-wave row reduction (over 16 cols-lanes), sigmoid, store ----
    // D[m][n]: n = lane&15, m = (lane>>4)*4 + reg  -> reduce across lane&15
    const float ob = b2s_;
    #pragma unroll
    for (int mt = 0; mt < 2; ++mt) {
        #pragma unroll
        for (int r = 0; r < 4; ++r) {
            float s = p2[mt][r];
            s += __shfl_xor(s, 1);
            s += __shfl_xor(s, 2);
            s += __shfl_xor(s, 4);
            s += __shfl_xor(s, 8);
            s = 1.0f / (1.0f + expf(-(s + ob)));
            if (llo == 0) {
                const int row = rowbase + mt * 16 + lhi * 4 + r;
                out[(size_t)row * NA + a] = s;
            }
        }
    }
}

extern "C" void kernel_launch(void* const* d_in, const int* in_sizes, int n_in,
                              void* d_out, int out_size, void* d_ws, size_t ws_size,
                              hipStream_t stream) {
    const float* x  = (const float*)d_in[0];
    const float* W1 = (const float*)d_in[1];
    const float* b1 = (const float*)d_in[2];
    const float* W2 = (const float*)d_in[3];
    const float* b2 = (const float*)d_in[4];
    float* out = (float*)d_out;

    dim3 grid(NA * NBT);   // 312 * 64 = 19968 blocks
    dim3 block(256);
    hipLaunchKernelGGL(attr_decoder_mfma, grid, block, 0, stream,
                       x, W1, b1, W2, b2, out);
}

// Round 3
// 178.130 us; speedup vs baseline: 3.5206x; 1.1781x over previous
//
#include <hip/hip_runtime.h>

#define NA   312      // attributes
#define LAT  64       // latent per attribute (K)
#define HID  128      // hidden per attribute (N)
#define NB   8192     // batch
#define MB   256      // rows per block
#define NBT  (NB / MB)   // 32 batch tiles
#define MT   4           // 16-row tiles per wave (4 waves * 64 rows = 256)

typedef __attribute__((ext_vector_type(8))) short bf16x8;
typedef __attribute__((ext_vector_type(4))) float f32x4;

// fp32 -> bf16, round-to-nearest-even (branch-free; inputs are finite)
__device__ inline short f2bf(float f) {
    unsigned u = __builtin_bit_cast(unsigned, f);
    u += 0x7FFFu + ((u >> 16) & 1u);
    return (short)(u >> 16);
}

// ---------------- prep: W1 [A][LAT][HID] fp32 -> frag-ordered bf16 ----------
// frag entry e = (nt*2+kk)*64 + lane holds 8 bf16:
//   element j = W1[a][ kk*32 + (lane>>4)*8 + j ][ nt*16 + (lane&15) ]
// so the main kernel's B-fragment load is ONE fully-coalesced dwordx4.
__global__ __launch_bounds__(256, 2) void prep_w1(
    const float* __restrict__ W1, short* __restrict__ w1f)
{
    __shared__ float lds[LAT * HID];   // 32 KB fp32
    const int a   = blockIdx.x;
    const int tid = threadIdx.x;

    const float4* src = reinterpret_cast<const float4*>(W1 + (size_t)a * (LAT * HID));
    float4* ldsv = reinterpret_cast<float4*>(lds);
    #pragma unroll
    for (int i = 0; i < (LAT * HID / 4) / 256; ++i)     // 8 iters, coalesced
        ldsv[i * 256 + tid] = src[i * 256 + tid];
    __syncthreads();

    bf16x8* dst = reinterpret_cast<bf16x8*>(w1f + (size_t)a * (LAT * HID));
    #pragma unroll
    for (int i = 0; i < 4; ++i) {
        const int e    = i * 256 + tid;
        const int nt   = e >> 7;
        const int kk   = (e >> 6) & 1;
        const int lane = e & 63;
        const int n  = nt * 16 + (lane & 15);
        const int k0 = kk * 32 + (lane >> 4) * 8;
        bf16x8 f;
        #pragma unroll
        for (int j = 0; j < 8; ++j)
            f[j] = f2bf(lds[(k0 + j) * HID + n]);
        dst[e] = f;   // consecutive e across tid -> coalesced 16 B stores
    }
}

// ---------------- main: no LDS, no barrier ----------------------------------
// One block: attribute a, 256 rows, 4 waves x 64 rows. Layer 1 = bf16 MFMA
// (A built in-register from global x; B = frag-ordered w1f, coalesced loads,
// L1/L2-resident). b1 folded into MFMA C-in. Layer 2 + sigmoid fp32 in-wave.
__global__ __launch_bounds__(256, 4) void attr_decoder_main(
    const float* __restrict__ x,
    const short* __restrict__ w1f,
    const float* __restrict__ b1,
    const float* __restrict__ W2,
    const float* __restrict__ b2,
    float* __restrict__ out)
{
    const int tid  = threadIdx.x;
    const int a    = blockIdx.x >> 5;        // /NBT; 32 consecutive blocks share w1f[a]
    const int bt   = blockIdx.x & (NBT - 1); // XCD = bt%8 for all a -> out-line write merge
    const int w    = tid >> 6;
    const int lane = tid & 63;
    const int llo  = lane & 15;
    const int lhi  = lane >> 4;
    const int rowbase = bt * MB + w * 64;

    // ---- A fragments: x rows straight from global, fp32 -> bf16 ----
    bf16x8 afrag[MT][2];
    #pragma unroll
    for (int mt = 0; mt < MT; ++mt) {
        const float* xrow = x + (size_t)(rowbase + mt * 16 + llo) * (NA * LAT)
                              + (size_t)a * LAT;
        #pragma unroll
        for (int kk = 0; kk < 2; ++kk) {
            const float4* p = reinterpret_cast<const float4*>(xrow + kk * 32 + lhi * 8);
            float4 v0 = p[0];
            float4 v1 = p[1];
            bf16x8 f;
            f[0] = f2bf(v0.x); f[1] = f2bf(v0.y); f[2] = f2bf(v0.z); f[3] = f2bf(v0.w);
            f[4] = f2bf(v1.x); f[5] = f2bf(v1.y); f[6] = f2bf(v1.z); f[7] = f2bf(v1.w);
            afrag[mt][kk] = f;
        }
    }

    // ---- layer 1 MFMA + fused layer-2 partials ----
    const bf16x8* wf = reinterpret_cast<const bf16x8*>(w1f + (size_t)a * (LAT * HID));
    const float*  b1a = b1 + a * HID;
    const float*  w2a = W2 + a * HID;   // W2 flat [A*HID]
    float p2[MT][4] = {};               // partial sums of relu(h)*w2
    #pragma unroll 2
    for (int nt = 0; nt < 8; ++nt) {
        const bf16x8 bf0 = wf[(nt * 2 + 0) * 64 + lane];   // coalesced 1 KB/instr
        const bf16x8 bf1 = wf[(nt * 2 + 1) * 64 + lane];
        const int n = nt * 16 + llo;
        const float b1v = b1a[n];
        const float w2v = w2a[n];
        const f32x4 cin = {b1v, b1v, b1v, b1v};   // D col = lane&15 -> same n all regs
        #pragma unroll
        for (int mt = 0; mt < MT; ++mt) {
            f32x4 acc = cin;
            acc = __builtin_amdgcn_mfma_f32_16x16x32_bf16(afrag[mt][0], bf0, acc, 0, 0, 0);
            acc = __builtin_amdgcn_mfma_f32_16x16x32_bf16(afrag[mt][1], bf1, acc, 0, 0, 0);
            #pragma unroll
            for (int r = 0; r < 4; ++r)
                p2[mt][r] = fmaf(fmaxf(acc[r], 0.f), w2v, p2[mt][r]);
        }
    }

    // ---- in-wave row reduction (over n-lanes), sigmoid, store ----
    const float ob = b2[a];
    #pragma unroll
    for (int mt = 0; mt < MT; ++mt) {
        #pragma unroll
        for (int r = 0; r < 4; ++r) {
            float s = p2[mt][r];
            s += __shfl_xor(s, 1);
            s += __shfl_xor(s, 2);
            s += __shfl_xor(s, 4);
            s += __shfl_xor(s, 8);
            s = 1.0f / (1.0f + expf(-(s + ob)));
            if (llo == 0) {
                const int row = rowbase + mt * 16 + lhi * 4 + r;
                out[(size_t)row * NA + a] = s;
            }
        }
    }
}

extern "C" void kernel_launch(void* const* d_in, const int* in_sizes, int n_in,
                              void* d_out, int out_size, void* d_ws, size_t ws_size,
                              hipStream_t stream) {
    const float* x  = (const float*)d_in[0];
    const float* W1 = (const float*)d_in[1];
    const float* b1 = (const float*)d_in[2];
    const float* W2 = (const float*)d_in[3];
    const float* b2 = (const float*)d_in[4];
    float* out = (float*)d_out;
    short* w1f = (short*)d_ws;          // 312*8192 bf16 = 5.1 MB (ws ~2.6 GB)

    hipLaunchKernelGGL(prep_w1, dim3(NA), dim3(256), 0, stream, W1, w1f);
    hipLaunchKernelGGL(attr_decoder_main, dim3(NA * NBT), dim3(256), 0, stream,
                       x, w1f, b1, W2, b2, out);
}